// Round 4
// baseline (1534.490 us; speedup 1.0000x reference)
//
#include <hip/hip_runtime.h>
#include <hip/hip_bf16.h>

// ---------------------------------------------------------------------------
// SpatialSelfAttention: GN(32) -> 1x1 QKV -> flash attention -> 1x1 out + res.
// B=8, C=512, N=4096. Attention fully fused (no S/P materialization).
// R4: flash rewritten: 32-key chunks, 2 barriers/iter, global_load_lds for
// K AND V via XOR-swizzled unpadded LDS, conditional O rescale.
// ---------------------------------------------------------------------------

typedef __bf16 bf16_t;
typedef __bf16 bf16x8 __attribute__((ext_vector_type(8)));
typedef __bf16 bf16x4 __attribute__((ext_vector_type(4)));
typedef float  f32x4  __attribute__((ext_vector_type(4)));

#define CDIM 512
#define NSP  4096
#define L2E  1.4426950408889634f

typedef __attribute__((address_space(1))) const void* as1_cvp;
typedef __attribute__((address_space(3))) void*       as3_vp;

__device__ __forceinline__ void gload_lds16(const void* g, void* l) {
  __builtin_amdgcn_global_load_lds((as1_cvp)g, (as3_vp)l, 16, 0, 0);
}

// ---------------------------------------------------------------------------
__global__ __launch_bounds__(256) void f32_to_bf16_k(const float* __restrict__ in,
                                                     bf16_t* __restrict__ out, int n) {
  int i = (blockIdx.x * 256 + threadIdx.x) * 4;
  if (i < n) {
    float4 v = *(const float4*)(in + i);
    bf16x4 o;
    o[0] = (bf16_t)v.x; o[1] = (bf16_t)v.y; o[2] = (bf16_t)v.z; o[3] = (bf16_t)v.w;
    *(bf16x4*)(out + i) = o;
  }
}

// ---------------------------------------------------------------------------
__global__ __launch_bounds__(256) void gn_stats_k(const float* __restrict__ x,
                                                  float* __restrict__ stats) {
  const int gid = blockIdx.x;  // b*32+g
  const float4* base = (const float4*)(x + (long)gid * 65536);
  float s = 0.f, ss = 0.f;
  for (int i = threadIdx.x; i < 16384; i += 256) {
    float4 t = base[i];
    s  += t.x + t.y + t.z + t.w;
    ss += t.x*t.x + t.y*t.y + t.z*t.z + t.w*t.w;
  }
#pragma unroll
  for (int o = 32; o; o >>= 1) { s += __shfl_xor(s, o); ss += __shfl_xor(ss, o); }
  __shared__ float rs[4], rss[4];
  const int lane = threadIdx.x & 63, wid = threadIdx.x >> 6;
  if (lane == 0) { rs[wid] = s; rss[wid] = ss; }
  __syncthreads();
  if (threadIdx.x == 0) {
    s  = rs[0] + rs[1] + rs[2] + rs[3];
    ss = rss[0] + rss[1] + rss[2] + rss[3];
    float mean = s * (1.f / 65536.f);
    float var  = ss * (1.f / 65536.f) - mean * mean;
    stats[gid]       = mean;
    stats[256 + gid] = rsqrtf(var + 1e-6f);
  }
}

// ---------------------------------------------------------------------------
__global__ __launch_bounds__(256) void gn_apply_k(const float* __restrict__ x,
                                                  const float* __restrict__ stats,
                                                  const float* __restrict__ gw,
                                                  const float* __restrict__ gb,
                                                  bf16_t* __restrict__ hnT) {
  __shared__ float tile[64 * 65];
  const int n0 = blockIdx.x * 64;
  const int c0 = blockIdx.y * 64;
  const int b  = blockIdx.z;
  const int tid = threadIdx.x;
  {
    const int cl = tid >> 2, nq = tid & 3;
    const int c = c0 + cl;
    const int g = c >> 4;
    const float mean = stats[b * 32 + g];
    const float rstd = stats[256 + b * 32 + g];
    const float a  = rstd * gw[c];
    const float bb = gb[c] - mean * a;
    const float4* xr = (const float4*)(x + ((long)b * CDIM + c) * NSP + n0 + nq * 16);
#pragma unroll
    for (int i = 0; i < 4; i++) {
      float4 t = xr[i];
      float* d = &tile[cl * 65 + nq * 16 + i * 4];
      d[0] = t.x * a + bb; d[1] = t.y * a + bb; d[2] = t.z * a + bb; d[3] = t.w * a + bb;
    }
  }
  __syncthreads();
  {
    const int nl = tid >> 2, cq = tid & 3;
    union { bf16_t h[16]; uint4 v[2]; } o;
#pragma unroll
    for (int j = 0; j < 16; j++) o.h[j] = (bf16_t)tile[(cq * 16 + j) * 65 + nl];
    bf16_t* dst = hnT + ((long)b * NSP + n0 + nl) * CDIM + c0 + cq * 16;
    ((uint4*)dst)[0] = o.v[0];
    ((uint4*)dst)[1] = o.v[1];
  }
}

// ---------------------------------------------------------------------------
// gemm_bt: C[m,n] = sum_k A[m,k]*B[n,k] (+bias) (*scale) (+residual)
// MODE 0: fp32 out. MODE 1: bf16 out. MODE 2: QK-split epilogue.
// ---------------------------------------------------------------------------
template <int MODE>
__global__ __launch_bounds__(256) void gemm_bt_k(
    const bf16_t* __restrict__ A, long sAb, long ldA,
    const bf16_t* __restrict__ B, long sBb, long ldB,
    void* __restrict__ Cout, long sCb, long ldC, void* __restrict__ Cout2,
    int M, int N, int K,
    const float* __restrict__ bias_row,
    const float* __restrict__ bias_col,
    float scale,
    const float* __restrict__ residual, long sRb) {
  __shared__ __align__(16) bf16_t sA[128 * 32];
  __shared__ __align__(16) bf16_t sB[128 * 32];

  const int tid  = threadIdx.x;
  const int lane = tid & 63;
  const int wid  = tid >> 6;
  const int wm = wid >> 1, wn = wid & 1;
  const int b = blockIdx.z;
  const int rowBase = blockIdx.y * 128;
  const int colBase = blockIdx.x * 128;

  const bf16_t* Ab = A + (long)b * sAb + (long)rowBase * ldA;
  const bf16_t* Bb = B + (long)b * sBb + (long)colBase * ldB;

  f32x4 acc[4][4];
#pragma unroll
  for (int i = 0; i < 4; i++)
#pragma unroll
    for (int j = 0; j < 4; j++) acc[i][j] = (f32x4){0.f, 0.f, 0.f, 0.f};

  const int q0 = tid, q1 = tid + 256;
  const int r0 = q0 >> 2, k0c = (q0 & 3) * 8;
  const int r1 = q1 >> 2, k1c = (q1 & 3) * 8;
  const int mrow  = lane & 15;
  const int kfrag = (lane >> 4) * 8;

  for (int kt = 0; kt < K; kt += 32) {
    gload_lds16(Ab + (long)r0 * ldA + kt + k0c, sA + q0 * 8);
    gload_lds16(Ab + (long)r1 * ldA + kt + k1c, sA + q1 * 8);
    gload_lds16(Bb + (long)r0 * ldB + kt + k0c, sB + q0 * 8);
    gload_lds16(Bb + (long)r1 * ldB + kt + k1c, sB + q1 * 8);
    __syncthreads();
    bf16x8 af[4], bfr[4];
#pragma unroll
    for (int t = 0; t < 4; t++) {
      af[t]  = *(const bf16x8*)&sA[(wm * 64 + t * 16 + mrow) * 32 + kfrag];
      bfr[t] = *(const bf16x8*)&sB[(wn * 64 + t * 16 + mrow) * 32 + kfrag];
    }
#pragma unroll
    for (int i = 0; i < 4; i++)
#pragma unroll
      for (int j = 0; j < 4; j++)
        acc[i][j] = __builtin_amdgcn_mfma_f32_16x16x32_bf16(af[i], bfr[j], acc[i][j], 0, 0, 0);
    __syncthreads();
  }

  const int quad = lane >> 4;
  const int colf = lane & 15;
#pragma unroll
  for (int i = 0; i < 4; i++) {
#pragma unroll
    for (int j = 0; j < 4; j++) {
#pragma unroll
      for (int r = 0; r < 4; r++) {
        const int row = rowBase + wm * 64 + i * 16 + quad * 4 + r;
        const int col = colBase + wn * 64 + j * 16 + colf;
        float v = acc[i][j][r];
        if (MODE == 2) {
          if (col < 512)
            ((bf16_t*)Cout)[(long)b * sCb + (long)row * ldC + col] =
                (bf16_t)((v + bias_col[col]) * scale);
          else
            ((bf16_t*)Cout2)[(long)b * sCb + (long)row * ldC + (col - 512)] =
                (bf16_t)(v + bias_row[col - 512]);
        } else {
          if (bias_row) v += bias_row[row];
          if (bias_col) v += bias_col[col];
          v *= scale;
          if (residual) v += residual[(long)b * sRb + (long)row * ldC + col];
          if (MODE == 1)
            ((bf16_t*)Cout)[(long)b * sCb + (long)row * ldC + col] = (bf16_t)v;
          else
            ((float*)Cout)[(long)b * sCb + (long)row * ldC + col] = v;
        }
      }
    }
  }
}

// ---------------------------------------------------------------------------
// Flash attention: O1T[b][n][c] = softmax_j(QT[n]·KT[j]) · V[:,j]
// Block = 4 waves x 16 Q-rows. 32-key chunks, 2 barriers/chunk.
// K: sK[32 keys][512 c] bf16, 16B-chunk index XOR (key&7)  -> global_load_lds
// V: sV[512 c][32 keys] bf16, 16B-chunk index XOR (c&3)    -> global_load_lds
// P: per-wave sP[16][40] (wave-private, no barrier). O in 128 regs/lane.
// LDS 70.7 KB -> 2 blocks/CU.
// ---------------------------------------------------------------------------
__global__ __launch_bounds__(256, 2) void flash_attn_k(
    const bf16_t* __restrict__ QT, const bf16_t* __restrict__ KT,
    const bf16_t* __restrict__ V, bf16_t* __restrict__ O1T) {
  __shared__ __align__(16) bf16_t sKV[32 * 512 + 512 * 32];  // sK | sV, 64 KiB
  __shared__ __align__(16) bf16_t sP[4][16 * 40];
  bf16_t* sK = sKV;
  bf16_t* sV = sKV + 32 * 512;

  const int tid = threadIdx.x, lane = tid & 63, w = tid >> 6;
  const int quad = lane >> 4, l15 = lane & 15;
  const int b = blockIdx.y, q0 = blockIdx.x * 64;

  const bf16_t* Qw = QT + ((long)b * NSP + q0 + w * 16) * CDIM;
  const bf16_t* Kb = KT + (long)b * NSP * CDIM;
  const bf16_t* Vb = V  + (long)b * NSP * CDIM;  // [512][4096]

  // persistent Q fragments: A[m=l15][k = kc*32 + quad*8 .. +7]
  bf16x8 qf[16];
#pragma unroll
  for (int kc = 0; kc < 16; kc++)
    qf[kc] = *(const bf16x8*)(Qw + (long)l15 * CDIM + kc * 32 + quad * 8);

  f32x4 oacc[32];
#pragma unroll
  for (int i = 0; i < 32; i++) oacc[i] = (f32x4){0.f, 0.f, 0.f, 0.f};
  float m_r[4] = {-3e38f, -3e38f, -3e38f, -3e38f};
  float l_r[4] = {0.f, 0.f, 0.f, 0.f};

  // precomputed lane offsets
  const int kswz = lane ^ 7;  // unused guard (kept simple below)
  (void)kswz;

  for (int j0 = 0; j0 < NSP; j0 += 32) {
    __syncthreads();  // all frag reads of previous chunk done

    // ---- stage K: 32 rows x 1 KiB; wave w stages keys w*8..w*8+7
#pragma unroll
    for (int i = 0; i < 8; i++) {
      const int key = w * 8 + i;
      const int ol = lane ^ (key & 7);  // 16B-chunk swizzle
      gload_lds16(Kb + (long)(j0 + key) * CDIM + ol * 8, sK + key * 512 + lane * 8);
    }
    // ---- stage V: [c][32 keys]; wave w stages channels w*128..w*128+127
#pragma unroll
    for (int j = 0; j < 8; j++) {
      const int cbase = w * 128 + j * 16;
      const int c = cbase + (lane >> 2);
      const int ol = (lane & 3) ^ (c & 3);
      gload_lds16(Vb + (long)c * NSP + j0 + ol * 8, sV + cbase * 32 + lane * 8);
    }
    __syncthreads();  // K+V ready (vmcnt drained by barrier)

    // ---- S = Q·K^T (scale folded into Q): 16q x 32 keys per wave
    f32x4 sacc[2];
    sacc[0] = (f32x4){0.f, 0.f, 0.f, 0.f};
    sacc[1] = (f32x4){0.f, 0.f, 0.f, 0.f};
#pragma unroll
    for (int kc = 0; kc < 16; kc++) {
#pragma unroll
      for (int t = 0; t < 2; t++) {
        const int key = t * 16 + l15;
        const int ch = (kc * 4 + quad) ^ (l15 & 7);
        bf16x8 kf = *(const bf16x8*)(sK + key * 512 + ch * 8);
        sacc[t] = __builtin_amdgcn_mfma_f32_16x16x32_bf16(qf[kc], kf, sacc[t], 0, 0, 0);
      }
    }

    // ---- online softmax (rows quad*4+r, cols over 16-lane group)
    float alpha[4];
#pragma unroll
    for (int r = 0; r < 4; r++) {
      float mx = fmaxf(sacc[0][r], sacc[1][r]);
      mx = fmaxf(mx, __shfl_xor(mx, 1));
      mx = fmaxf(mx, __shfl_xor(mx, 2));
      mx = fmaxf(mx, __shfl_xor(mx, 4));
      mx = fmaxf(mx, __shfl_xor(mx, 8));
      const float mn = fmaxf(m_r[r], mx);
      alpha[r] = exp2f((m_r[r] - mn) * L2E);
      m_r[r] = mn;
      float rs = 0.f;
#pragma unroll
      for (int t = 0; t < 2; t++) {
        const float p = exp2f((sacc[t][r] - mn) * L2E);
        sacc[t][r] = p;
        rs += p;
      }
      rs += __shfl_xor(rs, 1); rs += __shfl_xor(rs, 2);
      rs += __shfl_xor(rs, 4); rs += __shfl_xor(rs, 8);
      l_r[r] = l_r[r] * alpha[r] + rs;
    }
    // conditional O rescale: alpha==1 on most chunks once max stabilizes
    const float aprod = alpha[0] * alpha[1] * alpha[2] * alpha[3];
    if (__any(aprod != 1.0f)) {
      const f32x4 av = {alpha[0], alpha[1], alpha[2], alpha[3]};
#pragma unroll
      for (int i = 0; i < 32; i++) oacc[i] *= av;
    }

    // ---- P -> wave-private LDS (C-layout scatter), read back as A-frag
#pragma unroll
    for (int t = 0; t < 2; t++)
#pragma unroll
      for (int r = 0; r < 4; r++)
        sP[w][(quad * 4 + r) * 40 + t * 16 + l15] = (bf16_t)sacc[t][r];
    const bf16x8 pf = *(const bf16x8*)(&sP[w][l15 * 40 + quad * 8]);

    // ---- O += P·V : 32 c-tiles, K=32 keys in one MFMA k-dim
#pragma unroll
    for (int ct = 0; ct < 32; ct++) {
      const int c = ct * 16 + l15;
      const int ch = quad ^ (l15 & 3);
      const bf16x8 vf = *(const bf16x8*)(sV + c * 32 + ch * 8);
      oacc[ct] = __builtin_amdgcn_mfma_f32_16x16x32_bf16(pf, vf, oacc[ct], 0, 0, 0);
    }
  }

  // ---- epilogue: normalize, stage O[64][512] over sKV, coalesced store
  const f32x4 linv = {1.f / l_r[0], 1.f / l_r[1], 1.f / l_r[2], 1.f / l_r[3]};
  __syncthreads();
#pragma unroll
  for (int ct = 0; ct < 32; ct++) {
    const f32x4 o = oacc[ct] * linv;
#pragma unroll
    for (int r = 0; r < 4; r++)
      sKV[(w * 16 + quad * 4 + r) * 512 + ct * 16 + l15] = (bf16_t)o[r];
  }
  __syncthreads();
  bf16_t* Ob = O1T + ((long)b * NSP + q0) * CDIM;
#pragma unroll
  for (int i = 0; i < 16; i++) {
    const int g = i * 256 + tid, row = g >> 6, off = g & 63;
    *(uint4*)(Ob + (long)row * CDIM + off * 8) = *(const uint4*)(sKV + row * 512 + off * 8);
  }
}

// ---------------------------------------------------------------------------
extern "C" void kernel_launch(void* const* d_in, const int* in_sizes, int n_in,
                              void* d_out, int out_size, void* d_ws, size_t ws_size,
                              hipStream_t stream) {
  const float* x        = (const float*)d_in[0];
  const float* gn_scale = (const float*)d_in[1];
  const float* gn_bias  = (const float*)d_in[2];
  const float* wq = (const float*)d_in[3];
  const float* bq = (const float*)d_in[4];
  const float* wk = (const float*)d_in[5];
  const float* bk = (const float*)d_in[6];
  const float* wv = (const float*)d_in[7];
  const float* bv = (const float*)d_in[8];
  const float* wo = (const float*)d_in[9];
  const float* bo = (const float*)d_in[10];
  float* out = (float*)d_out;

  // ---- workspace layout, total ~130 MiB ----
  const long PB = 2097152;  // per-batch elems of [4096,512] / [512,4096]
  const long MB = 1048576L;
  char* w = (char*)d_ws;
  bf16_t* hnT  = (bf16_t*)(w);              //   0..32 MiB
  bf16_t* O1T  = hnT;                       //   aliases hnT (dead after projs)
  bf16_t* QT   = (bf16_t*)(w + 32 * MB);    //  32..64
  bf16_t* KT   = (bf16_t*)(w + 64 * MB);    //  64..96
  bf16_t* V    = (bf16_t*)(w + 96 * MB);    //  96..128
  bf16_t* wqkb = (bf16_t*)(w + 128 * MB);   // stacked [1024,512] bf16 (1 MiB)
  bf16_t* wvb  = (bf16_t*)(w + 129 * MB);
  bf16_t* wob  = (bf16_t*)(w + 129 * MB + 524288L);
  float*  stats = (float*)(w + 130 * MB);   // 512 floats

  const float qscale = 0.044194173824159216f;  // 512^-0.5

  f32_to_bf16_k<<<256, 256, 0, stream>>>(wq, wqkb, 262144);
  f32_to_bf16_k<<<256, 256, 0, stream>>>(wk, wqkb + 262144, 262144);
  f32_to_bf16_k<<<256, 256, 0, stream>>>(wv, wvb, 262144);
  f32_to_bf16_k<<<256, 256, 0, stream>>>(wo, wob, 262144);

  gn_stats_k<<<256, 256, 0, stream>>>(x, stats);
  gn_apply_k<<<dim3(64, 8, 8), 256, 0, stream>>>(x, stats, gn_scale, gn_bias, hnT);

  // QT/KT[b][n][c] in one dispatch (stacked weights), scale folded into Q
  gemm_bt_k<2><<<dim3(8, 32, 8), 256, 0, stream>>>(
      hnT, PB, 512, wqkb, 0, 512, QT, PB, 512, KT, 4096, 1024, 512,
      bk, bq, qscale, nullptr, 0);
  // V[b][c][n] = wv . hnT^T + bv
  gemm_bt_k<1><<<dim3(32, 4, 8), 256, 0, stream>>>(
      wvb, 0, 512, hnT, PB, 512, V, PB, 4096, nullptr, 512, 4096, 512,
      bv, nullptr, 1.f, nullptr, 0);

  // fused attention -> O1T[b][n][c]
  flash_attn_k<<<dim3(64, 8), 256, 0, stream>>>(QT, KT, V, O1T);

  // out[b][c][n] = wo . O1T^T + bo + x
  gemm_bt_k<0><<<dim3(32, 4, 8), 256, 0, stream>>>(
      wob, 0, 512, O1T, PB, 512, (void*)out, PB, 4096, nullptr, 512, 4096, 512,
      bo, nullptr, 1.f, x, PB);
}

// Round 5
// 1388.244 us; speedup vs baseline: 1.1053x; 1.1053x over previous
//
#include <hip/hip_runtime.h>
#include <hip/hip_bf16.h>

// ---------------------------------------------------------------------------
// SpatialSelfAttention: GN(32) -> 1x1 QKV -> flash attention -> 1x1 out + res.
// B=8, C=512, N=4096.
// R5: flash = DMA double-buffered pipeline, ONE barrier per 32-key chunk:
//   barrier -> issue global_load_lds prefetch(t+1) -> compute(t).
// Per-chunk compute (S/softmax/P/PV) identical to R4 (correctness-verified).
// LDS 133 KB -> 1 block/CU, latency hidden by prefetch not occupancy.
// ---------------------------------------------------------------------------

typedef __bf16 bf16_t;
typedef __bf16 bf16x8 __attribute__((ext_vector_type(8)));
typedef __bf16 bf16x4 __attribute__((ext_vector_type(4)));
typedef float  f32x4  __attribute__((ext_vector_type(4)));

#define CDIM 512
#define NSP  4096
#define L2E  1.4426950408889634f

typedef __attribute__((address_space(1))) const void* as1_cvp;
typedef __attribute__((address_space(3))) void*       as3_vp;

__device__ __forceinline__ void gload_lds16(const void* g, void* l) {
  __builtin_amdgcn_global_load_lds((as1_cvp)g, (as3_vp)l, 16, 0, 0);
}

// ---------------------------------------------------------------------------
__global__ __launch_bounds__(256) void f32_to_bf16_k(const float* __restrict__ in,
                                                     bf16_t* __restrict__ out, int n) {
  int i = (blockIdx.x * 256 + threadIdx.x) * 4;
  if (i < n) {
    float4 v = *(const float4*)(in + i);
    bf16x4 o;
    o[0] = (bf16_t)v.x; o[1] = (bf16_t)v.y; o[2] = (bf16_t)v.z; o[3] = (bf16_t)v.w;
    *(bf16x4*)(out + i) = o;
  }
}

// ---------------------------------------------------------------------------
__global__ __launch_bounds__(256) void gn_stats_k(const float* __restrict__ x,
                                                  float* __restrict__ stats) {
  const int gid = blockIdx.x;  // b*32+g
  const float4* base = (const float4*)(x + (long)gid * 65536);
  float s = 0.f, ss = 0.f;
  for (int i = threadIdx.x; i < 16384; i += 256) {
    float4 t = base[i];
    s  += t.x + t.y + t.z + t.w;
    ss += t.x*t.x + t.y*t.y + t.z*t.z + t.w*t.w;
  }
#pragma unroll
  for (int o = 32; o; o >>= 1) { s += __shfl_xor(s, o); ss += __shfl_xor(ss, o); }
  __shared__ float rs[4], rss[4];
  const int lane = threadIdx.x & 63, wid = threadIdx.x >> 6;
  if (lane == 0) { rs[wid] = s; rss[wid] = ss; }
  __syncthreads();
  if (threadIdx.x == 0) {
    s  = rs[0] + rs[1] + rs[2] + rs[3];
    ss = rss[0] + rss[1] + rss[2] + rss[3];
    float mean = s * (1.f / 65536.f);
    float var  = ss * (1.f / 65536.f) - mean * mean;
    stats[gid]       = mean;
    stats[256 + gid] = rsqrtf(var + 1e-6f);
  }
}

// ---------------------------------------------------------------------------
__global__ __launch_bounds__(256) void gn_apply_k(const float* __restrict__ x,
                                                  const float* __restrict__ stats,
                                                  const float* __restrict__ gw,
                                                  const float* __restrict__ gb,
                                                  bf16_t* __restrict__ hnT) {
  __shared__ float tile[64 * 65];
  const int n0 = blockIdx.x * 64;
  const int c0 = blockIdx.y * 64;
  const int b  = blockIdx.z;
  const int tid = threadIdx.x;
  {
    const int cl = tid >> 2, nq = tid & 3;
    const int c = c0 + cl;
    const int g = c >> 4;
    const float mean = stats[b * 32 + g];
    const float rstd = stats[256 + b * 32 + g];
    const float a  = rstd * gw[c];
    const float bb = gb[c] - mean * a;
    const float4* xr = (const float4*)(x + ((long)b * CDIM + c) * NSP + n0 + nq * 16);
#pragma unroll
    for (int i = 0; i < 4; i++) {
      float4 t = xr[i];
      float* d = &tile[cl * 65 + nq * 16 + i * 4];
      d[0] = t.x * a + bb; d[1] = t.y * a + bb; d[2] = t.z * a + bb; d[3] = t.w * a + bb;
    }
  }
  __syncthreads();
  {
    const int nl = tid >> 2, cq = tid & 3;
    union { bf16_t h[16]; uint4 v[2]; } o;
#pragma unroll
    for (int j = 0; j < 16; j++) o.h[j] = (bf16_t)tile[(cq * 16 + j) * 65 + nl];
    bf16_t* dst = hnT + ((long)b * NSP + n0 + nl) * CDIM + c0 + cq * 16;
    ((uint4*)dst)[0] = o.v[0];
    ((uint4*)dst)[1] = o.v[1];
  }
}

// ---------------------------------------------------------------------------
// gemm_bt: C[m,n] = sum_k A[m,k]*B[n,k] (+bias) (*scale) (+residual)
// MODE 0: fp32 out. MODE 1: bf16 out. MODE 2: QK-split epilogue.
// ---------------------------------------------------------------------------
template <int MODE>
__global__ __launch_bounds__(256) void gemm_bt_k(
    const bf16_t* __restrict__ A, long sAb, long ldA,
    const bf16_t* __restrict__ B, long sBb, long ldB,
    void* __restrict__ Cout, long sCb, long ldC, void* __restrict__ Cout2,
    int M, int N, int K,
    const float* __restrict__ bias_row,
    const float* __restrict__ bias_col,
    float scale,
    const float* __restrict__ residual, long sRb) {
  __shared__ __align__(16) bf16_t sA[128 * 32];
  __shared__ __align__(16) bf16_t sB[128 * 32];

  const int tid  = threadIdx.x;
  const int lane = tid & 63;
  const int wid  = tid >> 6;
  const int wm = wid >> 1, wn = wid & 1;
  const int b = blockIdx.z;
  const int rowBase = blockIdx.y * 128;
  const int colBase = blockIdx.x * 128;

  const bf16_t* Ab = A + (long)b * sAb + (long)rowBase * ldA;
  const bf16_t* Bb = B + (long)b * sBb + (long)colBase * ldB;

  f32x4 acc[4][4];
#pragma unroll
  for (int i = 0; i < 4; i++)
#pragma unroll
    for (int j = 0; j < 4; j++) acc[i][j] = (f32x4){0.f, 0.f, 0.f, 0.f};

  const int q0 = tid, q1 = tid + 256;
  const int r0 = q0 >> 2, k0c = (q0 & 3) * 8;
  const int r1 = q1 >> 2, k1c = (q1 & 3) * 8;
  const int mrow  = lane & 15;
  const int kfrag = (lane >> 4) * 8;

  for (int kt = 0; kt < K; kt += 32) {
    gload_lds16(Ab + (long)r0 * ldA + kt + k0c, sA + q0 * 8);
    gload_lds16(Ab + (long)r1 * ldA + kt + k1c, sA + q1 * 8);
    gload_lds16(Bb + (long)r0 * ldB + kt + k0c, sB + q0 * 8);
    gload_lds16(Bb + (long)r1 * ldB + kt + k1c, sB + q1 * 8);
    __syncthreads();
    bf16x8 af[4], bfr[4];
#pragma unroll
    for (int t = 0; t < 4; t++) {
      af[t]  = *(const bf16x8*)&sA[(wm * 64 + t * 16 + mrow) * 32 + kfrag];
      bfr[t] = *(const bf16x8*)&sB[(wn * 64 + t * 16 + mrow) * 32 + kfrag];
    }
#pragma unroll
    for (int i = 0; i < 4; i++)
#pragma unroll
      for (int j = 0; j < 4; j++)
        acc[i][j] = __builtin_amdgcn_mfma_f32_16x16x32_bf16(af[i], bfr[j], acc[i][j], 0, 0, 0);
    __syncthreads();
  }

  const int quad = lane >> 4;
  const int colf = lane & 15;
#pragma unroll
  for (int i = 0; i < 4; i++) {
#pragma unroll
    for (int j = 0; j < 4; j++) {
#pragma unroll
      for (int r = 0; r < 4; r++) {
        const int row = rowBase + wm * 64 + i * 16 + quad * 4 + r;
        const int col = colBase + wn * 64 + j * 16 + colf;
        float v = acc[i][j][r];
        if (MODE == 2) {
          if (col < 512)
            ((bf16_t*)Cout)[(long)b * sCb + (long)row * ldC + col] =
                (bf16_t)((v + bias_col[col]) * scale);
          else
            ((bf16_t*)Cout2)[(long)b * sCb + (long)row * ldC + (col - 512)] =
                (bf16_t)(v + bias_row[col - 512]);
        } else {
          if (bias_row) v += bias_row[row];
          if (bias_col) v += bias_col[col];
          v *= scale;
          if (residual) v += residual[(long)b * sRb + (long)row * ldC + col];
          if (MODE == 1)
            ((bf16_t*)Cout)[(long)b * sCb + (long)row * ldC + col] = (bf16_t)v;
          else
            ((float*)Cout)[(long)b * sCb + (long)row * ldC + col] = v;
        }
      }
    }
  }
}

// ---------------------------------------------------------------------------
// Flash attention, DMA double-buffered: O1T[b][n][c].
// Block = 4 waves x 16 Q-rows; 32-key chunks; per chunk:
//   __syncthreads(); issue gload_lds prefetch(next chunk); compute(current).
// The barrier's vmcnt drain hits a DMA that had a full compute phase to land.
// K: sK[2][32 key][512 c], global-side XOR swizzle on 16B chunks (key&7).
// V: sV[2][512 c][32 key], global-side XOR swizzle ((c>>2)&3).
// LDS 133 KB -> 1 block/CU.
// ---------------------------------------------------------------------------
__global__ __launch_bounds__(256, 1) void flash_attn_k(
    const bf16_t* __restrict__ QT, const bf16_t* __restrict__ KT,
    const bf16_t* __restrict__ V, bf16_t* __restrict__ O1T) {
  __shared__ __align__(16) bf16_t sK[2 * 32 * 512];   // 64 KiB
  __shared__ __align__(16) bf16_t sV[2 * 512 * 32];   // 64 KiB
  __shared__ __align__(16) bf16_t sP[4][16 * 40];     // 5 KiB

  const int tid = threadIdx.x, lane = tid & 63, w = tid >> 6;
  const int quad = lane >> 4, l15 = lane & 15;
  const int b = blockIdx.y, q0 = blockIdx.x * 64;

  const bf16_t* Qw = QT + ((long)b * NSP + q0 + w * 16) * CDIM;
  const bf16_t* Kb = KT + (long)b * NSP * CDIM;
  const bf16_t* Vb = V  + (long)b * NSP * CDIM;  // [512][4096]

  // persistent Q fragments: A[m=l15][k = kc*32 + quad*8 .. +7]
  bf16x8 qf[16];
#pragma unroll
  for (int kc = 0; kc < 16; kc++)
    qf[kc] = *(const bf16x8*)(Qw + (long)l15 * CDIM + kc * 32 + quad * 8);

  f32x4 oacc[32];
#pragma unroll
  for (int i = 0; i < 32; i++) oacc[i] = (f32x4){0.f, 0.f, 0.f, 0.f};
  float m_r[4] = {-3e38f, -3e38f, -3e38f, -3e38f};
  float l_r[4] = {0.f, 0.f, 0.f, 0.f};

  auto stage = [&](int buf, int j0) {
    bf16_t* dK = sK + buf * (32 * 512);
    bf16_t* dV = sV + buf * (512 * 32);
#pragma unroll
    for (int i = 0; i < 8; i++) {
      const int key = w * 8 + i;
      const int ol = lane ^ (key & 7);  // global-side 16B-chunk swizzle
      gload_lds16(Kb + (long)(j0 + key) * CDIM + ol * 8, dK + key * 512 + lane * 8);
    }
#pragma unroll
    for (int j = 0; j < 8; j++) {
      const int cbase = w * 128 + j * 16;
      const int c = cbase + (lane >> 2);
      const int ol = (lane & 3) ^ ((c >> 2) & 3);
      gload_lds16(Vb + (long)c * NSP + j0 + ol * 8, dV + cbase * 32 + lane * 8);
    }
  };

  stage(0, 0);  // cold-start prefetch

  for (int j0 = 0; j0 < NSP; j0 += 32) {
    const int cur = (j0 >> 5) & 1;
    __syncthreads();  // buf[cur] DMA landed; buf[cur^1] readers done
    if (j0 + 32 < NSP) stage(cur ^ 1, j0 + 32);  // prefetch next (no wait)

    const bf16_t* kcur = sK + cur * (32 * 512);
    const bf16_t* vcur = sV + cur * (512 * 32);

    // ---- S = Q·K^T (scale folded into Q): 16q x 32 keys per wave
    f32x4 sacc[2];
    sacc[0] = (f32x4){0.f, 0.f, 0.f, 0.f};
    sacc[1] = (f32x4){0.f, 0.f, 0.f, 0.f};
#pragma unroll
    for (int kc = 0; kc < 16; kc++) {
#pragma unroll
      for (int t = 0; t < 2; t++) {
        const int key = t * 16 + l15;
        const int ch = (kc * 4 + quad) ^ (l15 & 7);
        bf16x8 kf = *(const bf16x8*)(kcur + key * 512 + ch * 8);
        sacc[t] = __builtin_amdgcn_mfma_f32_16x16x32_bf16(qf[kc], kf, sacc[t], 0, 0, 0);
      }
    }

    // ---- online softmax (rows quad*4+r, cols over 16-lane group)
    float alpha[4];
#pragma unroll
    for (int r = 0; r < 4; r++) {
      float mx = fmaxf(sacc[0][r], sacc[1][r]);
      mx = fmaxf(mx, __shfl_xor(mx, 1));
      mx = fmaxf(mx, __shfl_xor(mx, 2));
      mx = fmaxf(mx, __shfl_xor(mx, 4));
      mx = fmaxf(mx, __shfl_xor(mx, 8));
      const float mn = fmaxf(m_r[r], mx);
      alpha[r] = exp2f((m_r[r] - mn) * L2E);
      m_r[r] = mn;
      float rs = 0.f;
#pragma unroll
      for (int t = 0; t < 2; t++) {
        const float p = exp2f((sacc[t][r] - mn) * L2E);
        sacc[t][r] = p;
        rs += p;
      }
      rs += __shfl_xor(rs, 1); rs += __shfl_xor(rs, 2);
      rs += __shfl_xor(rs, 4); rs += __shfl_xor(rs, 8);
      l_r[r] = l_r[r] * alpha[r] + rs;
    }
    const float aprod = alpha[0] * alpha[1] * alpha[2] * alpha[3];
    if (__any(aprod != 1.0f)) {
      const f32x4 av = {alpha[0], alpha[1], alpha[2], alpha[3]};
#pragma unroll
      for (int i = 0; i < 32; i++) oacc[i] *= av;
    }

    // ---- P -> wave-private LDS (C-layout scatter), read back as A-frag
#pragma unroll
    for (int t = 0; t < 2; t++)
#pragma unroll
      for (int r = 0; r < 4; r++)
        sP[w][(quad * 4 + r) * 40 + t * 16 + l15] = (bf16_t)sacc[t][r];
    const bf16x8 pf = *(const bf16x8*)(&sP[w][l15 * 40 + quad * 8]);

    // ---- O += P·V : 32 c-tiles, K=32 keys in one MFMA k-dim
#pragma unroll
    for (int ct = 0; ct < 32; ct++) {
      const int c = ct * 16 + l15;
      const int ch = quad ^ ((c >> 2) & 3);
      const bf16x8 vf = *(const bf16x8*)(vcur + c * 32 + ch * 8);
      oacc[ct] = __builtin_amdgcn_mfma_f32_16x16x32_bf16(pf, vf, oacc[ct], 0, 0, 0);
    }
  }

  // ---- epilogue: normalize, stage O[64][512] over sK (both buffers), store
  const f32x4 linv = {1.f / l_r[0], 1.f / l_r[1], 1.f / l_r[2], 1.f / l_r[3]};
  __syncthreads();
#pragma unroll
  for (int ct = 0; ct < 32; ct++) {
    const f32x4 o = oacc[ct] * linv;
#pragma unroll
    for (int r = 0; r < 4; r++)
      sK[(w * 16 + quad * 4 + r) * 512 + ct * 16 + l15] = (bf16_t)o[r];
  }
  __syncthreads();
  bf16_t* Ob = O1T + ((long)b * NSP + q0) * CDIM;
#pragma unroll
  for (int i = 0; i < 16; i++) {
    const int g = i * 256 + tid, row = g >> 6, off = g & 63;
    *(uint4*)(Ob + (long)row * CDIM + off * 8) = *(const uint4*)(sK + row * 512 + off * 8);
  }
}

// ---------------------------------------------------------------------------
extern "C" void kernel_launch(void* const* d_in, const int* in_sizes, int n_in,
                              void* d_out, int out_size, void* d_ws, size_t ws_size,
                              hipStream_t stream) {
  const float* x        = (const float*)d_in[0];
  const float* gn_scale = (const float*)d_in[1];
  const float* gn_bias  = (const float*)d_in[2];
  const float* wq = (const float*)d_in[3];
  const float* bq = (const float*)d_in[4];
  const float* wk = (const float*)d_in[5];
  const float* bk = (const float*)d_in[6];
  const float* wv = (const float*)d_in[7];
  const float* bv = (const float*)d_in[8];
  const float* wo = (const float*)d_in[9];
  const float* bo = (const float*)d_in[10];
  float* out = (float*)d_out;

  // ---- workspace layout, total ~130 MiB ----
  const long PB = 2097152;  // per-batch elems of [4096,512] / [512,4096]
  const long MB = 1048576L;
  char* w = (char*)d_ws;
  bf16_t* hnT  = (bf16_t*)(w);              //   0..32 MiB
  bf16_t* O1T  = hnT;                       //   aliases hnT (dead after projs)
  bf16_t* QT   = (bf16_t*)(w + 32 * MB);    //  32..64
  bf16_t* KT   = (bf16_t*)(w + 64 * MB);    //  64..96
  bf16_t* V    = (bf16_t*)(w + 96 * MB);    //  96..128
  bf16_t* wqkb = (bf16_t*)(w + 128 * MB);   // stacked [1024,512] bf16 (1 MiB)
  bf16_t* wvb  = (bf16_t*)(w + 129 * MB);
  bf16_t* wob  = (bf16_t*)(w + 129 * MB + 524288L);
  float*  stats = (float*)(w + 130 * MB);   // 512 floats

  const float qscale = 0.044194173824159216f;  // 512^-0.5

  f32_to_bf16_k<<<256, 256, 0, stream>>>(wq, wqkb, 262144);
  f32_to_bf16_k<<<256, 256, 0, stream>>>(wk, wqkb + 262144, 262144);
  f32_to_bf16_k<<<256, 256, 0, stream>>>(wv, wvb, 262144);
  f32_to_bf16_k<<<256, 256, 0, stream>>>(wo, wob, 262144);

  gn_stats_k<<<256, 256, 0, stream>>>(x, stats);
  gn_apply_k<<<dim3(64, 8, 8), 256, 0, stream>>>(x, stats, gn_scale, gn_bias, hnT);

  // QT/KT[b][n][c] in one dispatch (stacked weights), scale folded into Q
  gemm_bt_k<2><<<dim3(8, 32, 8), 256, 0, stream>>>(
      hnT, PB, 512, wqkb, 0, 512, QT, PB, 512, KT, 4096, 1024, 512,
      bk, bq, qscale, nullptr, 0);
  // V[b][c][n] = wv . hnT^T + bv
  gemm_bt_k<1><<<dim3(32, 4, 8), 256, 0, stream>>>(
      wvb, 0, 512, hnT, PB, 512, V, PB, 4096, nullptr, 512, 4096, 512,
      bv, nullptr, 1.f, nullptr, 0);

  // fused attention -> O1T[b][n][c]
  flash_attn_k<<<dim3(64, 8), 256, 0, stream>>>(QT, KT, V, O1T);

  // out[b][c][n] = wo . O1T^T + bo + x
  gemm_bt_k<0><<<dim3(32, 4, 8), 256, 0, stream>>>(
      wob, 0, 512, O1T, PB, 512, (void*)out, PB, 4096, nullptr, 512, 4096, 512,
      bo, nullptr, 1.f, x, PB);
}